// Round 7
// baseline (2484.412 us; speedup 1.0000x reference)
//
#include <hip/hip_runtime.h>
#include <math.h>

#define NB 32
#define NC 72
#define NT 1000
#define NF 64
#define NH 512
#define NCLS 3

// ---- workspace layout (float indices) ----
#define OFF_FEATS   0            // feats[b][t][f], 32*1000*64
#define OFF_POOLED  2048000      // pooled[b][h], 32*512
#define OFF_HX      2064384      // u64 hx[2][b][h] = {epoch:32|float:32}
#define WS_FLOATS   2129920

// pad every 32 h-elements by 4 slots: 16 p-chunks land 2-way on banks (free per m136)
#define HIDX2(k) ((k) + (((k) >> 5) << 2))
#define HPAD (NH + 64)

// ---------------- prep: epoch reset (MUST run every launch/replay) ----
__global__ void prep_kernel(unsigned long long* __restrict__ hx) {
  int i = blockIdx.x * 256 + threadIdx.x;
  if (i < 2 * NB * NH) hx[i] = 0ull;   // stale epochs would satisfy exact-match polls
}

// ---------------- fused front-end: conv5 + BN1 + ELU + spatial + BN2 + ELU ----
__global__ __launch_bounds__(256) void frontend_kernel(
    const float* __restrict__ x, const float* __restrict__ w_temp,
    const float* __restrict__ g1, const float* __restrict__ be1,
    const float* __restrict__ m1, const float* __restrict__ v1,
    const float* __restrict__ wsp,
    const float* __restrict__ g2, const float* __restrict__ be2,
    const float* __restrict__ m2, const float* __restrict__ v2,
    float* __restrict__ feats) {
  const int b = blockIdx.y;
  const int t0 = blockIdx.x * 64;

  __shared__ float xs[NC][68];
  for (int idx = threadIdx.x; idx < NC * 68; idx += 256) {
    int c = idx / 68, tt = idx % 68;
    int tg = t0 - 2 + tt;
    xs[c][tt] = (tg >= 0 && tg < NT) ? x[(b * NC + c) * NT + tg] : 0.0f;
  }
  __syncthreads();

  const int f = threadIdx.x & 63;
  const int tq = threadIdx.x >> 6;

  const float w0 = w_temp[f * 5 + 0], w1 = w_temp[f * 5 + 1], w2 = w_temp[f * 5 + 2],
              w3 = w_temp[f * 5 + 3], w4 = w_temp[f * 5 + 4];
  const float sc1 = g1[f] * rsqrtf(v1[f] + 1e-5f);
  const float sh1 = be1[f] - m1[f] * sc1;
  const float sc2 = g2[f] * rsqrtf(v2[f] + 1e-5f);
  const float sh2 = be2[f] - m2[f] * sc2;

  for (int i = 0; i < 16; ++i) {
    const int tl = tq + 4 * i;
    const int t = t0 + tl;
    if (t >= NT) break;
    float acc = 0.0f;
    for (int c = 0; c < NC; ++c) {
      const float* xr = &xs[c][tl];
      float conv = xr[0] * w0 + xr[1] * w1 + xr[2] * w2 + xr[3] * w3 + xr[4] * w4;
      float bn = conv * sc1 + sh1;
      float e = bn > 0.0f ? bn : __expf(bn) - 1.0f;
      acc += e * wsp[f * NC + c];
    }
    float bn2 = acc * sc2 + sh2;
    float e2 = bn2 > 0.0f ? bn2 : __expf(bn2) - 1.0f;
    feats[(b * NT + t) * NF + f] = e2;
  }
}

// ---------------- ESN scan: 16 batch-pairs x 4 col-groups, 2 batches per WG ----
// grid 64: pr = bid&15 (batches pr, pr+16), m = bid>>4 (128 cols each).
// Domain members {pr, pr+16, pr+32, pr+48} are congruent mod 8 -> same-XCD heuristic.
// b1's compute fills b0's publish->visible transit window; poll order b0-then-b1
// gives b1's transit the poll-b0 time as extra cover.
__global__ __launch_bounds__(512, 1) void esn_scan(
    const float* __restrict__ Wm, const float* __restrict__ w_in,
    const float* __restrict__ b_in, const float* __restrict__ feats,
    unsigned long long* __restrict__ hx, float* __restrict__ pooled) {
  const int pr = blockIdx.x & 15;
  const int m = blockIdx.x >> 4;    // col-group 0..3
  const int b0 = pr, b1 = pr + 16;
  const int tid = threadIdx.x;      // 0..511
  const int grp = tid >> 4;         // 0..31
  const int p = tid & 15;           // k-chunk / f-chunk
  const int c0 = m * 128 + grp * 4; // base column of this thread's 4 cols

  __shared__ __align__(16) float h2[2][2][HPAD];  // [parity][batch]
  __shared__ __align__(16) float f2[2][2][NF];

  // W slice: 4 cols x k in [p*32, p*32+32)  (r4-exact load + pin)
  float w[4][32];
#pragma unroll
  for (int c = 0; c < 4; ++c)
#pragma unroll
    for (int i = 0; i < 32; i += 4) {
      float4 t = *(const float4*)&Wm[(c0 + c) * NH + p * 32 + i];
      w[c][i] = t.x; w[c][i + 1] = t.y; w[c][i + 2] = t.z; w[c][i + 3] = t.w;
    }
#pragma unroll
  for (int c = 0; c < 4; ++c)
#pragma unroll
    for (int i = 0; i < 32; ++i) asm volatile("" : "+v"(w[c][i]));

  float wu[4][4];
#pragma unroll
  for (int c = 0; c < 4; ++c) {
    float4 t = *(const float4*)&w_in[(c0 + c) * NF + p * 4];
    wu[c][0] = t.x; wu[c][1] = t.y; wu[c][2] = t.z; wu[c][3] = t.w;
  }
  float be[4];
  {
    float4 bv = *(const float4*)&b_in[c0];
    be[0] = p == 0 ? bv.x : 0.0f; be[1] = p == 0 ? bv.y : 0.0f;
    be[2] = p == 0 ? bv.z : 0.0f; be[3] = p == 0 ? bv.w : 0.0f;
  }

  for (int i = tid; i < HPAD; i += 512) { h2[0][0][i] = 0.0f; h2[0][1][i] = 0.0f; }
  if (tid < NF) f2[0][0][tid] = feats[(b0 * NT) * NF + tid];
  else if (tid < 2 * NF) f2[0][1][tid - NF] = feats[(b1 * NT) * NF + (tid - NF)];
  __syncthreads();

  float* hc0 = &h2[0][0][0]; float* hb0 = &h2[1][0][0];
  float* hc1 = &h2[0][1][0]; float* hb1 = &h2[1][1][0];
  float* fc0 = &f2[0][0][0]; float* fb0 = &f2[1][0][0];
  float* fc1 = &f2[0][1][0]; float* fb1 = &f2[1][1][0];

  float pool0 = 0.0f, pool1 = 0.0f;
  int budget = 1000000;  // safety: degrade to wrong-answer instead of hang

#pragma unroll 1
  for (int t = 0; t < NT; ++t) {
    const int par = (t + 1) & 1;
    unsigned long long* hxb0 = hx + par * (NB * NH) + b0 * NH;
    unsigned long long* hxb1 = hx + par * (NB * NH) + b1 * NH;
    const unsigned epoch = (unsigned)(t + 1);

    // ---- batch 0: matvec + butterfly + publish ----
    {
      float acc[4] = {be[0], be[1], be[2], be[3]};
      float4 fv = *(const float4*)&fc0[p * 4];
#pragma unroll
      for (int c = 0; c < 4; ++c)
        acc[c] += fv.x * wu[c][0] + fv.y * wu[c][1] + fv.z * wu[c][2] + fv.w * wu[c][3];
#pragma unroll
      for (int i = 0; i < 8; ++i) {
        float4 hv = *(const float4*)&hc0[p * 36 + i * 4];
#pragma unroll
        for (int c = 0; c < 4; ++c)
          acc[c] += hv.x * w[c][i * 4] + hv.y * w[c][i * 4 + 1] +
                    hv.z * w[c][i * 4 + 2] + hv.w * w[c][i * 4 + 3];
      }
#pragma unroll
      for (int c = 0; c < 4; ++c) {
        acc[c] += __shfl_xor(acc[c], 1);
        acc[c] += __shfl_xor(acc[c], 2);
        acc[c] += __shfl_xor(acc[c], 4);
        acc[c] += __shfl_xor(acc[c], 8);
      }
      if (p < 4) {
        const int j = c0 + p;
        float asel = p == 0 ? acc[0] : p == 1 ? acc[1] : p == 2 ? acc[2] : acc[3];
        float hn = 0.9f * hc0[HIDX2(j)] + 0.1f * tanhf(asel);
        pool0 += hn;
        if (t < NT - 1) {
          unsigned long long pk =
              ((unsigned long long)epoch << 32) | (unsigned)__float_as_uint(hn);
          __hip_atomic_store(&hxb0[j], pk, __ATOMIC_RELAXED, __HIP_MEMORY_SCOPE_AGENT);
          hb0[HIDX2(j)] = hn;
        }
      }
    }
    // ---- batch 1: matvec + butterfly + publish (fills b0's transit window) ----
    {
      float acc[4] = {be[0], be[1], be[2], be[3]};
      float4 fv = *(const float4*)&fc1[p * 4];
#pragma unroll
      for (int c = 0; c < 4; ++c)
        acc[c] += fv.x * wu[c][0] + fv.y * wu[c][1] + fv.z * wu[c][2] + fv.w * wu[c][3];
#pragma unroll
      for (int i = 0; i < 8; ++i) {
        float4 hv = *(const float4*)&hc1[p * 36 + i * 4];
#pragma unroll
        for (int c = 0; c < 4; ++c)
          acc[c] += hv.x * w[c][i * 4] + hv.y * w[c][i * 4 + 1] +
                    hv.z * w[c][i * 4 + 2] + hv.w * w[c][i * 4 + 3];
      }
#pragma unroll
      for (int c = 0; c < 4; ++c) {
        acc[c] += __shfl_xor(acc[c], 1);
        acc[c] += __shfl_xor(acc[c], 2);
        acc[c] += __shfl_xor(acc[c], 4);
        acc[c] += __shfl_xor(acc[c], 8);
      }
      if (p < 4) {
        const int j = c0 + p;
        float asel = p == 0 ? acc[0] : p == 1 ? acc[1] : p == 2 ? acc[2] : acc[3];
        float hn = 0.9f * hc1[HIDX2(j)] + 0.1f * tanhf(asel);
        pool1 += hn;
        if (t < NT - 1) {
          unsigned long long pk =
              ((unsigned long long)epoch << 32) | (unsigned)__float_as_uint(hn);
          __hip_atomic_store(&hxb1[j], pk, __ATOMIC_RELAXED, __HIP_MEMORY_SCOPE_AGENT);
          hb1[HIDX2(j)] = hn;
        }
      }
    }
    if (t == NT - 1) break;

    // prefetch next feats rows; latency hides under the poll
    float fn = 0.0f;
    if (tid < NF) fn = feats[(b0 * NT + t + 1) * NF + tid];
    else if (tid < 2 * NF) fn = feats[(b1 * NT + t + 1) * NF + (tid - NF)];

    const int k = tid;                  // 512 threads cover the 512 h-values
    if ((k >> 7) != m) {                // poll the other 3 groups, both batches
      unsigned long long q0 = 0, q1 = 0;
      bool d0 = false, d1 = false;
      for (;;) {
        if (!d0) {
          q0 = __hip_atomic_load(&hxb0[k], __ATOMIC_RELAXED, __HIP_MEMORY_SCOPE_AGENT);
          d0 = ((unsigned)(q0 >> 32) == epoch);
        }
        if (!d1) {
          q1 = __hip_atomic_load(&hxb1[k], __ATOMIC_RELAXED, __HIP_MEMORY_SCOPE_AGENT);
          d1 = ((unsigned)(q1 >> 32) == epoch);
        }
        if (d0 && d1) break;
        if (--budget < 0) break;
        __builtin_amdgcn_s_sleep(1);
      }
      hb0[HIDX2(k)] = __uint_as_float((unsigned)q0);
      hb1[HIDX2(k)] = __uint_as_float((unsigned)q1);
    }
    if (tid < NF) fb0[tid] = fn;
    else if (tid < 2 * NF) fb1[tid - NF] = fn;
    __syncthreads();                    // ONE barrier per step
    { float* tp = hc0; hc0 = hb0; hb0 = tp; }
    { float* tp = hc1; hc1 = hb1; hb1 = tp; }
    { float* tp = fc0; fc0 = fb0; fb0 = tp; }
    { float* tp = fc1; fc1 = fb1; fb1 = tp; }
  }

  if (p < 4) {
    pooled[b0 * NH + c0 + p] = pool0 * (1.0f / NT);
    pooled[b1 * NH + c0 + p] = pool1 * (1.0f / NT);
  }
}

// ---------------- classifier head ----
__global__ void classifier_kernel(const float* __restrict__ pooled,
                                  const float* __restrict__ w_cls,
                                  const float* __restrict__ b_cls,
                                  float* __restrict__ out) {
  const int b = blockIdx.x;
  const int lane = threadIdx.x;  // 64
  float a0 = 0.0f, a1 = 0.0f, a2 = 0.0f;
  for (int jj = lane; jj < NH; jj += 64) {
    float pv = pooled[b * NH + jj];
    a0 += pv * w_cls[0 * NH + jj];
    a1 += pv * w_cls[1 * NH + jj];
    a2 += pv * w_cls[2 * NH + jj];
  }
  for (int off = 32; off; off >>= 1) {
    a0 += __shfl_down(a0, off);
    a1 += __shfl_down(a1, off);
    a2 += __shfl_down(a2, off);
  }
  if (lane == 0) {
    out[b * NCLS + 0] = a0 + b_cls[0];
    out[b * NCLS + 1] = a1 + b_cls[1];
    out[b * NCLS + 2] = a2 + b_cls[2];
  }
}

extern "C" void kernel_launch(void* const* d_in, const int* in_sizes, int n_in,
                              void* d_out, int out_size, void* d_ws, size_t ws_size,
                              hipStream_t stream) {
  (void)in_sizes; (void)n_in; (void)out_size;
  if (ws_size < (size_t)WS_FLOATS * 4) return;

  const float* x      = (const float*)d_in[0];
  const float* w_temp = (const float*)d_in[1];
  const float* g1  = (const float*)d_in[2];
  const float* be1 = (const float*)d_in[3];
  const float* m1  = (const float*)d_in[4];
  const float* v1  = (const float*)d_in[5];
  const float* wsp = (const float*)d_in[6];
  const float* g2  = (const float*)d_in[7];
  const float* be2 = (const float*)d_in[8];
  const float* m2  = (const float*)d_in[9];
  const float* v2  = (const float*)d_in[10];
  const float* w_in  = (const float*)d_in[11];
  const float* b_in  = (const float*)d_in[12];
  const float* Wm    = (const float*)d_in[13];
  const float* w_cls = (const float*)d_in[14];
  const float* b_cls = (const float*)d_in[15];

  float* ws_f  = (float*)d_ws;
  float* feats = ws_f + OFF_FEATS;
  float* pooledp = ws_f + OFF_POOLED;
  unsigned long long* hx = (unsigned long long*)(ws_f + OFF_HX);

  prep_kernel<<<128, 256, 0, stream>>>(hx);

  dim3 gfe(16, NB);
  frontend_kernel<<<gfe, 256, 0, stream>>>(x, w_temp, g1, be1, m1, v1, wsp,
                                           g2, be2, m2, v2, feats);

  esn_scan<<<64, 512, 0, stream>>>(Wm, w_in, b_in, feats, hx, pooledp);

  classifier_kernel<<<NB, 64, 0, stream>>>(pooledp, w_cls, b_cls, (float*)d_out);
}